// Round 1
// baseline (5672.672 us; speedup 1.0000x reference)
//
#include <hip/hip_runtime.h>

// Problem constants (match reference)
#define NN 100000
#define DD 128
#define EE 1600000

// ---------------------------------------------------------------------------
// SpMM via atomic scatter: out[row[e]] += vals[e] * x[col[e]]
// 32 lanes per edge, each lane handles one float4 (4 of 128 dims).
// ---------------------------------------------------------------------------
__global__ __launch_bounds__(256) void spmm_atomic(
    const float4* __restrict__ x, const float* __restrict__ vals,
    const int* __restrict__ row, const int* __restrict__ col,
    float* __restrict__ out, int E)
{
    int t = blockIdx.x * 256 + threadIdx.x;
    int e = t >> 5;
    if (e >= E) return;
    int d4 = t & 31;

    float v = vals[e];
    int r = row[e];
    int c = col[e];

    float4 xv = x[(size_t)c * 32 + d4];
    float* o = out + (size_t)r * DD + d4 * 4;
    __hip_atomic_fetch_add(o + 0, v * xv.x, __ATOMIC_RELAXED, __HIP_MEMORY_SCOPE_AGENT);
    __hip_atomic_fetch_add(o + 1, v * xv.y, __ATOMIC_RELAXED, __HIP_MEMORY_SCOPE_AGENT);
    __hip_atomic_fetch_add(o + 2, v * xv.z, __ATOMIC_RELAXED, __HIP_MEMORY_SCOPE_AGENT);
    __hip_atomic_fetch_add(o + 3, v * xv.w, __ATOMIC_RELAXED, __HIP_MEMORY_SCOPE_AGENT);
}

// ---------------------------------------------------------------------------
// Fused dense: for each hop o: vw = relu(H_o @ W_o + b_o); per-row batchnorm;
// accumulate sum of the 3 normalized outputs. 32 rows/block, 256 threads,
// 4x4 register micro-tile per thread. W_o staged in LDS (64KB), H tile 16KB.
// ---------------------------------------------------------------------------
__device__ __forceinline__ void dense_pass(
    const float* __restrict__ H, const float* __restrict__ W,
    const float* __restrict__ bias, const float* __restrict__ off,
    const float* __restrict__ sc,
    float* Ws, float* Hs, int tid, int rbase, int r0, int c0,
    float acc[4][4])
{
    // Stage W (128x128 f32, 64KB): linear float4 copy, coalesced.
    const float4* Wg = (const float4*)W;
    float4* Wl = (float4*)Ws;
    #pragma unroll
    for (int i = 0; i < 16; i++) Wl[tid + i * 256] = Wg[tid + i * 256];

    // Stage H tile (32x128 f32, 16KB): linear float4 copy.
    const float4* Hg = (const float4*)(H + (size_t)rbase * DD);
    float4* Hl = (float4*)Hs;
    #pragma unroll
    for (int i = 0; i < 4; i++) Hl[tid + i * 256] = Hg[tid + i * 256];
    __syncthreads();

    float4 bb = *(const float4*)(bias + c0);
    float vw[4][4];
    #pragma unroll
    for (int r = 0; r < 4; r++) {
        vw[r][0] = bb.x; vw[r][1] = bb.y; vw[r][2] = bb.z; vw[r][3] = bb.w;
    }

    // K-loop: 4x4 outer product per 4-k chunk.
    #pragma unroll 4
    for (int k = 0; k < DD; k += 4) {
        float4 w0 = *(const float4*)(Ws + (k + 0) * DD + c0);
        float4 w1 = *(const float4*)(Ws + (k + 1) * DD + c0);
        float4 w2 = *(const float4*)(Ws + (k + 2) * DD + c0);
        float4 w3 = *(const float4*)(Ws + (k + 3) * DD + c0);
        #pragma unroll
        for (int r = 0; r < 4; r++) {
            float4 h = *(const float4*)(Hs + (r0 + r) * DD + k);
            vw[r][0] += h.x * w0.x + h.y * w1.x + h.z * w2.x + h.w * w3.x;
            vw[r][1] += h.x * w0.y + h.y * w1.y + h.z * w2.y + h.w * w3.y;
            vw[r][2] += h.x * w0.z + h.y * w1.z + h.z * w2.z + h.w * w3.z;
            vw[r][3] += h.x * w0.w + h.y * w1.w + h.z * w2.w + h.w * w3.w;
        }
    }

    float4 scc = *(const float4*)(sc + c0);
    float4 offc = *(const float4*)(off + c0);
    float sx[4] = {scc.x, scc.y, scc.z, scc.w};
    float ox[4] = {offc.x, offc.y, offc.z, offc.w};

    #pragma unroll
    for (int r = 0; r < 4; r++) {
        #pragma unroll
        for (int c = 0; c < 4; c++) vw[r][c] = fmaxf(vw[r][c], 0.f);
        float s = vw[r][0] + vw[r][1] + vw[r][2] + vw[r][3];
        float q = vw[r][0] * vw[r][0] + vw[r][1] * vw[r][1]
                + vw[r][2] * vw[r][2] + vw[r][3] * vw[r][3];
        // Reduce over the 32-lane column group (masks < 32 stay in-half).
        #pragma unroll
        for (int m = 1; m <= 16; m <<= 1) {
            s += __shfl_xor(s, m, 64);
            q += __shfl_xor(q, m, 64);
        }
        float mean = s * 0.0078125f;              // /128
        float var  = q * 0.0078125f - mean * mean;
        float rs   = rsqrtf(var + 1e-9f);
        #pragma unroll
        for (int c = 0; c < 4; c++)
            acc[r][c] += sx[c] * (vw[r][c] - mean) * rs + ox[c];
    }
    __syncthreads();  // protect LDS before next pass overwrites
}

__global__ __launch_bounds__(256) void fused_dense(
    const float* __restrict__ h0, const float* __restrict__ h1,
    const float* __restrict__ h2,
    const float* __restrict__ W0, const float* __restrict__ W1,
    const float* __restrict__ W2,
    const float* __restrict__ b0, const float* __restrict__ b1,
    const float* __restrict__ b2,
    const float* __restrict__ off0, const float* __restrict__ off1,
    const float* __restrict__ off2,
    const float* __restrict__ sc0, const float* __restrict__ sc1,
    const float* __restrict__ sc2,
    float* __restrict__ out)
{
    __shared__ float Ws[DD * DD];    // 64 KB
    __shared__ float Hs[32 * DD];    // 16 KB

    const int tid = threadIdx.x;
    const int r0 = (tid >> 5) * 4;       // 0..28
    const int c0 = (tid & 31) * 4;       // 0..124
    const int rbase = blockIdx.x * 32;

    float acc[4][4];
    #pragma unroll
    for (int r = 0; r < 4; r++)
        #pragma unroll
        for (int c = 0; c < 4; c++) acc[r][c] = 0.f;

    dense_pass(h0, W0, b0, off0, sc0, Ws, Hs, tid, rbase, r0, c0, acc);
    dense_pass(h1, W1, b1, off1, sc1, Ws, Hs, tid, rbase, r0, c0, acc);
    dense_pass(h2, W2, b2, off2, sc2, Ws, Hs, tid, rbase, r0, c0, acc);

    #pragma unroll
    for (int r = 0; r < 4; r++) {
        float4 v = make_float4(acc[r][0], acc[r][1], acc[r][2], acc[r][3]);
        *(float4*)(out + (size_t)(rbase + r0 + r) * DD + c0) = v;
    }
}

extern "C" void kernel_launch(void* const* d_in, const int* in_sizes, int n_in,
                              void* d_out, int out_size, void* d_ws, size_t ws_size,
                              hipStream_t stream)
{
    const float* vecs = (const float*)d_in[0];
    const float* adj  = (const float*)d_in[1];
    const int*   row  = (const int*)d_in[2];
    const int*   col  = (const int*)d_in[3];
    const float* W0   = (const float*)d_in[4];
    const float* b0   = (const float*)d_in[5];
    const float* off0 = (const float*)d_in[6];
    const float* sc0  = (const float*)d_in[7];
    const float* W1   = (const float*)d_in[8];
    const float* b1   = (const float*)d_in[9];
    const float* off1 = (const float*)d_in[10];
    const float* sc1  = (const float*)d_in[11];
    const float* W2   = (const float*)d_in[12];
    const float* b2   = (const float*)d_in[13];
    const float* off2 = (const float*)d_in[14];
    const float* sc2  = (const float*)d_in[15];

    const int E = in_sizes[1];

    float* hop1 = (float*)d_ws;
    float* hop2 = hop1 + (size_t)NN * DD;

    // Zero hop accumulators (ws is re-poisoned before every call).
    hipMemsetAsync(d_ws, 0, (size_t)2 * NN * DD * sizeof(float), stream);

    int spmm_blocks = (E * 32 + 255) / 256;
    spmm_atomic<<<spmm_blocks, 256, 0, stream>>>(
        (const float4*)vecs, adj, row, col, hop1, E);
    spmm_atomic<<<spmm_blocks, 256, 0, stream>>>(
        (const float4*)hop1, adj, row, col, hop2, E);

    fused_dense<<<NN / 32, 256, 0, stream>>>(
        vecs, hop1, hop2, W0, W1, W2, b0, b1, b2,
        off0, off1, off2, sc0, sc1, sc2, (float*)d_out);
}

// Round 2
// 954.732 us; speedup vs baseline: 5.9416x; 5.9416x over previous
//
#include <hip/hip_runtime.h>

#define NN 100000
#define DD 128

// ---------------------------------------------------------------------------
// CSR build: histogram -> single-block scan -> scatter (row-sorted col/val)
// ---------------------------------------------------------------------------
__global__ __launch_bounds__(256) void hist_rows(
    const int* __restrict__ row, int* __restrict__ cnt, int E)
{
    int e = blockIdx.x * 256 + threadIdx.x;
    if (e < E) atomicAdd(&cnt[row[e]], 1);
}

// Single block, 1024 threads. cnt==cursor array (in-place rewrite is safe:
// each thread reads its chunk element before overwriting it).
__global__ __launch_bounds__(1024) void scan_rows(
    int* __restrict__ cnt, int* __restrict__ row_ptr, int* __restrict__ cursor,
    int N)
{
    __shared__ int part[1024];
    const int t = threadIdx.x;
    const int chunk = (N + 1023) / 1024;
    const int base = t * chunk;

    int sum = 0;
    for (int i = 0; i < chunk; i++) {
        int idx = base + i;
        if (idx < N) sum += cnt[idx];
    }
    part[t] = sum;
    __syncthreads();
    // inclusive Hillis-Steele scan over 1024 partials
    for (int off = 1; off < 1024; off <<= 1) {
        int v = (t >= off) ? part[t - off] : 0;
        __syncthreads();
        part[t] += v;
        __syncthreads();
    }
    int run = (t > 0) ? part[t - 1] : 0;   // exclusive prefix
    for (int i = 0; i < chunk; i++) {
        int idx = base + i;
        if (idx < N) {
            int c = cnt[idx];
            row_ptr[idx] = run;
            cursor[idx] = run;
            run += c;
        }
    }
    if (t == 1023) row_ptr[N] = part[1023];
}

__global__ __launch_bounds__(256) void scatter_edges(
    const int* __restrict__ row, const int* __restrict__ col,
    const float* __restrict__ vals, int* __restrict__ cursor,
    int* __restrict__ colp, float* __restrict__ valp, int E)
{
    int e = blockIdx.x * 256 + threadIdx.x;
    if (e < E) {
        int r = row[e];
        int p = atomicAdd(&cursor[r], 1);
        colp[p] = col[e];
        valp[p] = vals[e];
    }
}

// ---------------------------------------------------------------------------
// Gather SpMM (CSR): one 64-lane wave per row, float2 per lane (128 dims).
// Inner loop unrolled x4 for memory-level parallelism on the gathers.
// ---------------------------------------------------------------------------
__global__ __launch_bounds__(256) void spmm_csr(
    const float2* __restrict__ x, const int* __restrict__ row_ptr,
    const int* __restrict__ colp, const float* __restrict__ valp,
    float2* __restrict__ out, int N)
{
    int w = (blockIdx.x * 256 + threadIdx.x) >> 6;
    int lane = threadIdx.x & 63;
    if (w >= N) return;

    int s = row_ptr[w];
    int t = row_ptr[w + 1];
    float2 acc = make_float2(0.f, 0.f);

    int e = s;
    for (; e + 4 <= t; e += 4) {
        int c0 = colp[e + 0], c1 = colp[e + 1], c2 = colp[e + 2], c3 = colp[e + 3];
        float v0 = valp[e + 0], v1 = valp[e + 1], v2 = valp[e + 2], v3 = valp[e + 3];
        float2 a = x[(size_t)c0 * 64 + lane];
        float2 b = x[(size_t)c1 * 64 + lane];
        float2 c = x[(size_t)c2 * 64 + lane];
        float2 d = x[(size_t)c3 * 64 + lane];
        acc.x += v0 * a.x + v1 * b.x + v2 * c.x + v3 * d.x;
        acc.y += v0 * a.y + v1 * b.y + v2 * c.y + v3 * d.y;
    }
    for (; e < t; e++) {
        int c0 = colp[e];
        float v0 = valp[e];
        float2 a = x[(size_t)c0 * 64 + lane];
        acc.x += v0 * a.x;
        acc.y += v0 * a.y;
    }
    out[(size_t)w * 64 + lane] = acc;
}

// ---------------------------------------------------------------------------
// Fused dense: vw = relu(H_o @ W_o + b_o); per-row batchnorm; sum over orders.
// 32 rows/block, 256 threads, 4x4 register micro-tile.
// ---------------------------------------------------------------------------
__device__ __forceinline__ void dense_pass(
    const float* __restrict__ H, const float* __restrict__ W,
    const float* __restrict__ bias, const float* __restrict__ off,
    const float* __restrict__ sc,
    float* Ws, float* Hs, int tid, int rbase, int r0, int c0,
    float acc[4][4])
{
    const float4* Wg = (const float4*)W;
    float4* Wl = (float4*)Ws;
    #pragma unroll
    for (int i = 0; i < 16; i++) Wl[tid + i * 256] = Wg[tid + i * 256];

    const float4* Hg = (const float4*)(H + (size_t)rbase * DD);
    float4* Hl = (float4*)Hs;
    #pragma unroll
    for (int i = 0; i < 4; i++) Hl[tid + i * 256] = Hg[tid + i * 256];
    __syncthreads();

    float4 bb = *(const float4*)(bias + c0);
    float vw[4][4];
    #pragma unroll
    for (int r = 0; r < 4; r++) {
        vw[r][0] = bb.x; vw[r][1] = bb.y; vw[r][2] = bb.z; vw[r][3] = bb.w;
    }

    #pragma unroll 4
    for (int k = 0; k < DD; k += 4) {
        float4 w0 = *(const float4*)(Ws + (k + 0) * DD + c0);
        float4 w1 = *(const float4*)(Ws + (k + 1) * DD + c0);
        float4 w2 = *(const float4*)(Ws + (k + 2) * DD + c0);
        float4 w3 = *(const float4*)(Ws + (k + 3) * DD + c0);
        #pragma unroll
        for (int r = 0; r < 4; r++) {
            float4 h = *(const float4*)(Hs + (r0 + r) * DD + k);
            vw[r][0] += h.x * w0.x + h.y * w1.x + h.z * w2.x + h.w * w3.x;
            vw[r][1] += h.x * w0.y + h.y * w1.y + h.z * w2.y + h.w * w3.y;
            vw[r][2] += h.x * w0.z + h.y * w1.z + h.z * w2.z + h.w * w3.z;
            vw[r][3] += h.x * w0.w + h.y * w1.w + h.z * w2.w + h.w * w3.w;
        }
    }

    float4 scc = *(const float4*)(sc + c0);
    float4 offc = *(const float4*)(off + c0);
    float sx[4] = {scc.x, scc.y, scc.z, scc.w};
    float ox[4] = {offc.x, offc.y, offc.z, offc.w};

    #pragma unroll
    for (int r = 0; r < 4; r++) {
        #pragma unroll
        for (int c = 0; c < 4; c++) vw[r][c] = fmaxf(vw[r][c], 0.f);
        float s = vw[r][0] + vw[r][1] + vw[r][2] + vw[r][3];
        float q = vw[r][0] * vw[r][0] + vw[r][1] * vw[r][1]
                + vw[r][2] * vw[r][2] + vw[r][3] * vw[r][3];
        #pragma unroll
        for (int m = 1; m <= 16; m <<= 1) {
            s += __shfl_xor(s, m, 64);
            q += __shfl_xor(q, m, 64);
        }
        float mean = s * 0.0078125f;
        float var  = q * 0.0078125f - mean * mean;
        float rs   = rsqrtf(var + 1e-9f);
        #pragma unroll
        for (int c = 0; c < 4; c++)
            acc[r][c] += sx[c] * (vw[r][c] - mean) * rs + ox[c];
    }
    __syncthreads();
}

__global__ __launch_bounds__(256) void fused_dense(
    const float* __restrict__ h0, const float* __restrict__ h1,
    const float* __restrict__ h2,
    const float* __restrict__ W0, const float* __restrict__ W1,
    const float* __restrict__ W2,
    const float* __restrict__ b0, const float* __restrict__ b1,
    const float* __restrict__ b2,
    const float* __restrict__ off0, const float* __restrict__ off1,
    const float* __restrict__ off2,
    const float* __restrict__ sc0, const float* __restrict__ sc1,
    const float* __restrict__ sc2,
    float* __restrict__ out)
{
    __shared__ float Ws[DD * DD];
    __shared__ float Hs[32 * DD];

    const int tid = threadIdx.x;
    const int r0 = (tid >> 5) * 4;
    const int c0 = (tid & 31) * 4;
    const int rbase = blockIdx.x * 32;

    float acc[4][4];
    #pragma unroll
    for (int r = 0; r < 4; r++)
        #pragma unroll
        for (int c = 0; c < 4; c++) acc[r][c] = 0.f;

    dense_pass(h0, W0, b0, off0, sc0, Ws, Hs, tid, rbase, r0, c0, acc);
    dense_pass(h1, W1, b1, off1, sc1, Ws, Hs, tid, rbase, r0, c0, acc);
    dense_pass(h2, W2, b2, off2, sc2, Ws, Hs, tid, rbase, r0, c0, acc);

    #pragma unroll
    for (int r = 0; r < 4; r++) {
        float4 v = make_float4(acc[r][0], acc[r][1], acc[r][2], acc[r][3]);
        *(float4*)(out + (size_t)(rbase + r0 + r) * DD + c0) = v;
    }
}

extern "C" void kernel_launch(void* const* d_in, const int* in_sizes, int n_in,
                              void* d_out, int out_size, void* d_ws, size_t ws_size,
                              hipStream_t stream)
{
    const float* vecs = (const float*)d_in[0];
    const float* adj  = (const float*)d_in[1];
    const int*   row  = (const int*)d_in[2];
    const int*   col  = (const int*)d_in[3];
    const float* W0   = (const float*)d_in[4];
    const float* b0   = (const float*)d_in[5];
    const float* off0 = (const float*)d_in[6];
    const float* sc0  = (const float*)d_in[7];
    const float* W1   = (const float*)d_in[8];
    const float* b1   = (const float*)d_in[9];
    const float* off1 = (const float*)d_in[10];
    const float* sc1  = (const float*)d_in[11];
    const float* W2   = (const float*)d_in[12];
    const float* b2   = (const float*)d_in[13];
    const float* off2 = (const float*)d_in[14];
    const float* sc2  = (const float*)d_in[15];

    const int E = in_sizes[1];
    const int N = NN;

    // Workspace layout
    float* hop1   = (float*)d_ws;                       // N*128 f32
    float* hop2   = hop1 + (size_t)N * DD;              // N*128 f32
    int*   row_ptr = (int*)(hop2 + (size_t)N * DD);     // N+1
    int*   cursor  = row_ptr + (N + 1);                 // N+1 (doubles as cnt)
    int*   colp    = cursor + (N + 1);                  // E
    float* valp    = (float*)(colp + E);                // E

    // counts <- 0 (cursor array doubles as the histogram buffer)
    hipMemsetAsync(cursor, 0, (size_t)N * sizeof(int), stream);

    int eb = (E + 255) / 256;
    hist_rows<<<eb, 256, 0, stream>>>(row, cursor, E);
    scan_rows<<<1, 1024, 0, stream>>>(cursor, row_ptr, cursor, N);
    scatter_edges<<<eb, 256, 0, stream>>>(row, col, adj, cursor, colp, valp, E);

    int sb = (N * 64 + 255) / 256;
    spmm_csr<<<sb, 256, 0, stream>>>(
        (const float2*)vecs, row_ptr, colp, valp, (float2*)hop1, N);
    spmm_csr<<<sb, 256, 0, stream>>>(
        (const float2*)hop1, row_ptr, colp, valp, (float2*)hop2, N);

    fused_dense<<<NN / 32, 256, 0, stream>>>(
        vecs, hop1, hop2, W0, W1, W2, b0, b1, b2,
        off0, off1, off2, sc0, sc1, sc2, (float*)d_out);
}

// Round 3
// 711.866 us; speedup vs baseline: 7.9687x; 1.3412x over previous
//
#include <hip/hip_runtime.h>

#define NN 100000
#define DD 128
#define RP_PAD 100004   // row_ptr/cursor stride, padded for 16B alignment

// ---------------------------------------------------------------------------
// CSR build: histogram -> 2-level scan -> scatter (row-sorted col/val)
// ---------------------------------------------------------------------------
__global__ __launch_bounds__(256) void hist_rows(
    const int* __restrict__ row, int* __restrict__ cnt, int E)
{
    int e = blockIdx.x * 256 + threadIdx.x;
    if (e < E) atomicAdd(&cnt[row[e]], 1);
}

// Level 1: each block sums 1024 counts (4/thread, int4 coalesced).
__global__ __launch_bounds__(256) void scan_partial(
    const int* __restrict__ cnt, int* __restrict__ blocksum, int N)
{
    int t = threadIdx.x;
    int gbase = blockIdx.x * 1024 + t * 4;
    int s = 0;
    if (gbase + 3 < N) {
        int4 v = *(const int4*)(cnt + gbase);
        s = v.x + v.y + v.z + v.w;
    } else {
        for (int i = 0; i < 4; i++) if (gbase + i < N) s += cnt[gbase + i];
    }
    #pragma unroll
    for (int m = 1; m < 64; m <<= 1) s += __shfl_xor(s, m, 64);
    __shared__ int ws[4];
    if ((t & 63) == 0) ws[t >> 6] = s;
    __syncthreads();
    if (t == 0) blocksum[blockIdx.x] = ws[0] + ws[1] + ws[2] + ws[3];
}

// Level 2: one small block scans the <=128 block sums (exclusive, in place)
// and writes row_ptr[N] = grand total.
__global__ __launch_bounds__(128) void scan_mid(
    int* __restrict__ blocksum, int* __restrict__ row_ptr, int nblocks, int N)
{
    __shared__ int sh[128];
    int t = threadIdx.x;
    int v = (t < nblocks) ? blocksum[t] : 0;
    sh[t] = v;
    __syncthreads();
    for (int off = 1; off < 128; off <<= 1) {
        int u = (t >= off) ? sh[t - off] : 0;
        __syncthreads();
        sh[t] += u;
        __syncthreads();
    }
    if (t < nblocks) blocksum[t] = sh[t] - v;   // exclusive
    if (t == 127) row_ptr[N] = sh[127];
}

// Level 3: per-block local exclusive scan + global block offset.
__global__ __launch_bounds__(256) void scan_local(
    const int* __restrict__ cnt, const int* __restrict__ blocksum,
    int* __restrict__ row_ptr, int* __restrict__ cursor, int N)
{
    int t = threadIdx.x;
    int gbase = blockIdx.x * 1024 + t * 4;
    int4 raw = make_int4(0, 0, 0, 0);
    if (gbase + 3 < N) {
        raw = *(const int4*)(cnt + gbase);
    } else {
        int* p = (int*)&raw;
        for (int i = 0; i < 4; i++) p[i] = (gbase + i < N) ? cnt[gbase + i] : 0;
    }
    int s = raw.x + raw.y + raw.z + raw.w;

    // inclusive wave scan over 64 lanes
    int lane = t & 63;
    int inc = s;
    #pragma unroll
    for (int off = 1; off < 64; off <<= 1) {
        int u = __shfl_up(inc, off, 64);
        if (lane >= off) inc += u;
    }
    __shared__ int wsum[4];
    if (lane == 63) wsum[t >> 6] = inc;
    __syncthreads();
    int woff = 0;
    int wid = t >> 6;
    for (int i = 0; i < wid; i++) woff += wsum[i];
    int excl = woff + inc - s;                    // block-local exclusive
    int base = blocksum[blockIdx.x] + excl;

    int r0 = base;
    int r1 = r0 + raw.x;
    int r2 = r1 + raw.y;
    int r3 = r2 + raw.z;
    if (gbase + 3 < N) {
        int4 o = make_int4(r0, r1, r2, r3);
        *(int4*)(row_ptr + gbase) = o;
        *(int4*)(cursor + gbase)  = o;
    } else {
        int o[4] = {r0, r1, r2, r3};
        for (int i = 0; i < 4; i++) if (gbase + i < N) {
            row_ptr[gbase + i] = o[i];
            cursor[gbase + i]  = o[i];
        }
    }
}

__global__ __launch_bounds__(256) void scatter_edges(
    const int* __restrict__ row, const int* __restrict__ col,
    const float* __restrict__ vals, int* __restrict__ cursor,
    int* __restrict__ colp, float* __restrict__ valp, int E)
{
    int e = blockIdx.x * 256 + threadIdx.x;
    if (e < E) {
        int r = row[e];
        int p = atomicAdd(&cursor[r], 1);
        colp[p] = col[e];
        valp[p] = vals[e];
    }
}

// ---------------------------------------------------------------------------
// Gather SpMM (CSR): one row per 32-lane group, float4 per lane (128 dims).
// Inner loop unrolled x4 for memory-level parallelism on the gathers.
// ---------------------------------------------------------------------------
__global__ __launch_bounds__(256) void spmm_csr(
    const float4* __restrict__ x, const int* __restrict__ row_ptr,
    const int* __restrict__ colp, const float* __restrict__ valp,
    float4* __restrict__ out, int N)
{
    int g = (blockIdx.x * 256 + threadIdx.x) >> 5;
    int lane = threadIdx.x & 31;
    if (g >= N) return;

    int s = row_ptr[g];
    int t = row_ptr[g + 1];
    float4 acc = make_float4(0.f, 0.f, 0.f, 0.f);

    int e = s;
    for (; e + 4 <= t; e += 4) {
        int c0 = colp[e + 0], c1 = colp[e + 1], c2 = colp[e + 2], c3 = colp[e + 3];
        float v0 = valp[e + 0], v1 = valp[e + 1], v2 = valp[e + 2], v3 = valp[e + 3];
        float4 a = x[(size_t)c0 * 32 + lane];
        float4 b = x[(size_t)c1 * 32 + lane];
        float4 c = x[(size_t)c2 * 32 + lane];
        float4 d = x[(size_t)c3 * 32 + lane];
        acc.x += v0 * a.x + v1 * b.x + v2 * c.x + v3 * d.x;
        acc.y += v0 * a.y + v1 * b.y + v2 * c.y + v3 * d.y;
        acc.z += v0 * a.z + v1 * b.z + v2 * c.z + v3 * d.z;
        acc.w += v0 * a.w + v1 * b.w + v2 * c.w + v3 * d.w;
    }
    for (; e < t; e++) {
        int c0 = colp[e];
        float v0 = valp[e];
        float4 a = x[(size_t)c0 * 32 + lane];
        acc.x += v0 * a.x; acc.y += v0 * a.y;
        acc.z += v0 * a.z; acc.w += v0 * a.w;
    }
    out[(size_t)g * 32 + lane] = acc;
}

// ---------------------------------------------------------------------------
// Fused dense: vw = relu(H_o @ W_o + b_o); per-row batchnorm; sum over orders.
// 32 rows/block, 256 threads, 4x4 register micro-tile.
// ---------------------------------------------------------------------------
__device__ __forceinline__ void dense_pass(
    const float* __restrict__ H, const float* __restrict__ W,
    const float* __restrict__ bias, const float* __restrict__ off,
    const float* __restrict__ sc,
    float* Ws, float* Hs, int tid, int rbase, int r0, int c0,
    float acc[4][4])
{
    const float4* Wg = (const float4*)W;
    float4* Wl = (float4*)Ws;
    #pragma unroll
    for (int i = 0; i < 16; i++) Wl[tid + i * 256] = Wg[tid + i * 256];

    const float4* Hg = (const float4*)(H + (size_t)rbase * DD);
    float4* Hl = (float4*)Hs;
    #pragma unroll
    for (int i = 0; i < 4; i++) Hl[tid + i * 256] = Hg[tid + i * 256];
    __syncthreads();

    float4 bb = *(const float4*)(bias + c0);
    float vw[4][4];
    #pragma unroll
    for (int r = 0; r < 4; r++) {
        vw[r][0] = bb.x; vw[r][1] = bb.y; vw[r][2] = bb.z; vw[r][3] = bb.w;
    }

    #pragma unroll 4
    for (int k = 0; k < DD; k += 4) {
        float4 w0 = *(const float4*)(Ws + (k + 0) * DD + c0);
        float4 w1 = *(const float4*)(Ws + (k + 1) * DD + c0);
        float4 w2 = *(const float4*)(Ws + (k + 2) * DD + c0);
        float4 w3 = *(const float4*)(Ws + (k + 3) * DD + c0);
        #pragma unroll
        for (int r = 0; r < 4; r++) {
            float4 h = *(const float4*)(Hs + (r0 + r) * DD + k);
            vw[r][0] += h.x * w0.x + h.y * w1.x + h.z * w2.x + h.w * w3.x;
            vw[r][1] += h.x * w0.y + h.y * w1.y + h.z * w2.y + h.w * w3.y;
            vw[r][2] += h.x * w0.z + h.y * w1.z + h.z * w2.z + h.w * w3.z;
            vw[r][3] += h.x * w0.w + h.y * w1.w + h.z * w2.w + h.w * w3.w;
        }
    }

    float4 scc = *(const float4*)(sc + c0);
    float4 offc = *(const float4*)(off + c0);
    float sx[4] = {scc.x, scc.y, scc.z, scc.w};
    float ox[4] = {offc.x, offc.y, offc.z, offc.w};

    #pragma unroll
    for (int r = 0; r < 4; r++) {
        #pragma unroll
        for (int c = 0; c < 4; c++) vw[r][c] = fmaxf(vw[r][c], 0.f);
        float s = vw[r][0] + vw[r][1] + vw[r][2] + vw[r][3];
        float q = vw[r][0] * vw[r][0] + vw[r][1] * vw[r][1]
                + vw[r][2] * vw[r][2] + vw[r][3] * vw[r][3];
        #pragma unroll
        for (int m = 1; m <= 16; m <<= 1) {
            s += __shfl_xor(s, m, 64);
            q += __shfl_xor(q, m, 64);
        }
        float mean = s * 0.0078125f;
        float var  = q * 0.0078125f - mean * mean;
        float rs   = rsqrtf(var + 1e-9f);
        #pragma unroll
        for (int c = 0; c < 4; c++)
            acc[r][c] += sx[c] * (vw[r][c] - mean) * rs + ox[c];
    }
    __syncthreads();
}

__global__ __launch_bounds__(256) void fused_dense(
    const float* __restrict__ h0, const float* __restrict__ h1,
    const float* __restrict__ h2,
    const float* __restrict__ W0, const float* __restrict__ W1,
    const float* __restrict__ W2,
    const float* __restrict__ b0, const float* __restrict__ b1,
    const float* __restrict__ b2,
    const float* __restrict__ off0, const float* __restrict__ off1,
    const float* __restrict__ off2,
    const float* __restrict__ sc0, const float* __restrict__ sc1,
    const float* __restrict__ sc2,
    float* __restrict__ out)
{
    __shared__ float Ws[DD * DD];
    __shared__ float Hs[32 * DD];

    const int tid = threadIdx.x;
    const int r0 = (tid >> 5) * 4;
    const int c0 = (tid & 31) * 4;
    const int rbase = blockIdx.x * 32;

    float acc[4][4];
    #pragma unroll
    for (int r = 0; r < 4; r++)
        #pragma unroll
        for (int c = 0; c < 4; c++) acc[r][c] = 0.f;

    dense_pass(h0, W0, b0, off0, sc0, Ws, Hs, tid, rbase, r0, c0, acc);
    dense_pass(h1, W1, b1, off1, sc1, Ws, Hs, tid, rbase, r0, c0, acc);
    dense_pass(h2, W2, b2, off2, sc2, Ws, Hs, tid, rbase, r0, c0, acc);

    #pragma unroll
    for (int r = 0; r < 4; r++) {
        float4 v = make_float4(acc[r][0], acc[r][1], acc[r][2], acc[r][3]);
        *(float4*)(out + (size_t)(rbase + r0 + r) * DD + c0) = v;
    }
}

extern "C" void kernel_launch(void* const* d_in, const int* in_sizes, int n_in,
                              void* d_out, int out_size, void* d_ws, size_t ws_size,
                              hipStream_t stream)
{
    const float* vecs = (const float*)d_in[0];
    const float* adj  = (const float*)d_in[1];
    const int*   row  = (const int*)d_in[2];
    const int*   col  = (const int*)d_in[3];
    const float* W0   = (const float*)d_in[4];
    const float* b0   = (const float*)d_in[5];
    const float* off0 = (const float*)d_in[6];
    const float* sc0  = (const float*)d_in[7];
    const float* W1   = (const float*)d_in[8];
    const float* b1   = (const float*)d_in[9];
    const float* off1 = (const float*)d_in[10];
    const float* sc1  = (const float*)d_in[11];
    const float* W2   = (const float*)d_in[12];
    const float* b2   = (const float*)d_in[13];
    const float* off2 = (const float*)d_in[14];
    const float* sc2  = (const float*)d_in[15];

    const int E = in_sizes[1];
    const int N = NN;

    // Workspace layout (all 16B-aligned)
    float* hop1    = (float*)d_ws;                      // N*128 f32
    float* hop2    = hop1 + (size_t)N * DD;             // N*128 f32
    int*   row_ptr = (int*)(hop2 + (size_t)N * DD);     // RP_PAD (uses N+1)
    int*   cursor  = row_ptr + RP_PAD;                  // RP_PAD (doubles as cnt)
    int*   colp    = cursor + RP_PAD;                   // E
    float* valp    = (float*)(colp + E);                // E
    int*   blocksum = (int*)(valp + E);                 // <=128

    hipMemsetAsync(cursor, 0, (size_t)N * sizeof(int), stream);

    const int snb = (N + 1023) / 1024;    // 98 scan blocks
    int eb = (E + 255) / 256;
    hist_rows<<<eb, 256, 0, stream>>>(row, cursor, E);
    scan_partial<<<snb, 256, 0, stream>>>(cursor, blocksum, N);
    scan_mid<<<1, 128, 0, stream>>>(blocksum, row_ptr, snb, N);
    scan_local<<<snb, 256, 0, stream>>>(cursor, blocksum, row_ptr, cursor, N);
    scatter_edges<<<eb, 256, 0, stream>>>(row, col, adj, cursor, colp, valp, E);

    int sb = (N * 32 + 255) / 256;
    spmm_csr<<<sb, 256, 0, stream>>>(
        (const float4*)vecs, row_ptr, colp, valp, (float4*)hop1, N);
    spmm_csr<<<sb, 256, 0, stream>>>(
        (const float4*)hop1, row_ptr, colp, valp, (float4*)hop2, N);

    fused_dense<<<NN / 32, 256, 0, stream>>>(
        vecs, hop1, hop2, W0, W1, W2, b0, b1, b2,
        off0, off1, off2, sc0, sc1, sc2, (float*)d_out);
}

// Round 4
// 541.257 us; speedup vs baseline: 10.4806x; 1.3152x over previous
//
#include <hip/hip_runtime.h>

#define NN 100000
#define DD 128
#define RP_PAD 100004   // row_ptr/cursor stride, padded for 16B alignment

typedef short bf16x8 __attribute__((ext_vector_type(8)));
typedef float f32x4  __attribute__((ext_vector_type(4)));

__device__ __forceinline__ unsigned f2bf_rne(float f) {
    unsigned u = __float_as_uint(f);
    return (u + 0x7FFFu + ((u >> 16) & 1u)) >> 16;
}
__device__ __forceinline__ unsigned packbf(float a, float b) {
    return f2bf_rne(a) | (f2bf_rne(b) << 16);
}
__device__ __forceinline__ float bf_lo(unsigned u) { return __uint_as_float(u << 16); }
__device__ __forceinline__ float bf_hi(unsigned u) { return __uint_as_float(u & 0xFFFF0000u); }

// ---------------------------------------------------------------------------
// CSR build: histogram -> 2-level scan -> scatter (row-sorted col/val)
// ---------------------------------------------------------------------------
__global__ __launch_bounds__(256) void hist_rows(
    const int* __restrict__ row, int* __restrict__ cnt, int E)
{
    int e = blockIdx.x * 256 + threadIdx.x;
    if (e < E) atomicAdd(&cnt[row[e]], 1);
}

__global__ __launch_bounds__(256) void scan_partial(
    const int* __restrict__ cnt, int* __restrict__ blocksum, int N)
{
    int t = threadIdx.x;
    int gbase = blockIdx.x * 1024 + t * 4;
    int s = 0;
    if (gbase + 3 < N) {
        int4 v = *(const int4*)(cnt + gbase);
        s = v.x + v.y + v.z + v.w;
    } else {
        for (int i = 0; i < 4; i++) if (gbase + i < N) s += cnt[gbase + i];
    }
    #pragma unroll
    for (int m = 1; m < 64; m <<= 1) s += __shfl_xor(s, m, 64);
    __shared__ int ws[4];
    if ((t & 63) == 0) ws[t >> 6] = s;
    __syncthreads();
    if (t == 0) blocksum[blockIdx.x] = ws[0] + ws[1] + ws[2] + ws[3];
}

__global__ __launch_bounds__(128) void scan_mid(
    int* __restrict__ blocksum, int* __restrict__ row_ptr, int nblocks, int N)
{
    __shared__ int sh[128];
    int t = threadIdx.x;
    int v = (t < nblocks) ? blocksum[t] : 0;
    sh[t] = v;
    __syncthreads();
    for (int off = 1; off < 128; off <<= 1) {
        int u = (t >= off) ? sh[t - off] : 0;
        __syncthreads();
        sh[t] += u;
        __syncthreads();
    }
    if (t < nblocks) blocksum[t] = sh[t] - v;   // exclusive
    if (t == 127) row_ptr[N] = sh[127];
}

__global__ __launch_bounds__(256) void scan_local(
    const int* __restrict__ cnt, const int* __restrict__ blocksum,
    int* __restrict__ row_ptr, int* __restrict__ cursor, int N)
{
    int t = threadIdx.x;
    int gbase = blockIdx.x * 1024 + t * 4;
    int4 raw = make_int4(0, 0, 0, 0);
    if (gbase + 3 < N) {
        raw = *(const int4*)(cnt + gbase);
    } else {
        int* p = (int*)&raw;
        for (int i = 0; i < 4; i++) p[i] = (gbase + i < N) ? cnt[gbase + i] : 0;
    }
    int s = raw.x + raw.y + raw.z + raw.w;

    int lane = t & 63;
    int inc = s;
    #pragma unroll
    for (int off = 1; off < 64; off <<= 1) {
        int u = __shfl_up(inc, off, 64);
        if (lane >= off) inc += u;
    }
    __shared__ int wsum[4];
    if (lane == 63) wsum[t >> 6] = inc;
    __syncthreads();
    int woff = 0;
    int wid = t >> 6;
    for (int i = 0; i < wid; i++) woff += wsum[i];
    int excl = woff + inc - s;
    int base = blocksum[blockIdx.x] + excl;

    int r0 = base;
    int r1 = r0 + raw.x;
    int r2 = r1 + raw.y;
    int r3 = r2 + raw.z;
    if (gbase + 3 < N) {
        int4 o = make_int4(r0, r1, r2, r3);
        *(int4*)(row_ptr + gbase) = o;
        *(int4*)(cursor + gbase)  = o;
    } else {
        int o[4] = {r0, r1, r2, r3};
        for (int i = 0; i < 4; i++) if (gbase + i < N) {
            row_ptr[gbase + i] = o[i];
            cursor[gbase + i]  = o[i];
        }
    }
}

__global__ __launch_bounds__(256) void scatter_edges(
    const int* __restrict__ row, const int* __restrict__ col,
    const float* __restrict__ vals, int* __restrict__ cursor,
    int* __restrict__ colp, float* __restrict__ valp, int E)
{
    int e = blockIdx.x * 256 + threadIdx.x;
    if (e < E) {
        int r = row[e];
        int p = atomicAdd(&cursor[r], 1);
        colp[p] = col[e];
        valp[p] = vals[e];
    }
}

// ---------------------------------------------------------------------------
// Converters
// ---------------------------------------------------------------------------
__global__ __launch_bounds__(256) void cvt_bf16(
    const float4* __restrict__ in, uint4* __restrict__ out, int n8)
{
    int t = blockIdx.x * 256 + threadIdx.x;
    if (t >= n8) return;
    float4 a = in[t * 2], b = in[t * 2 + 1];
    uint4 o;
    o.x = packbf(a.x, a.y); o.y = packbf(a.z, a.w);
    o.z = packbf(b.x, b.y); o.w = packbf(b.z, b.w);
    out[t] = o;
}

// W[k][n] f32 -> Wt[n][k] bf16 (one 128x128 matrix; 2048 threads)
__global__ __launch_bounds__(256) void cvt_w(
    const float* __restrict__ W, unsigned short* __restrict__ Wt)
{
    int idx = blockIdx.x * 256 + threadIdx.x;   // 0..2047
    int n = idx >> 4;
    int kc = (idx & 15) * 8;
    unsigned r[4];
    #pragma unroll
    for (int j = 0; j < 4; j++) {
        float a = W[(kc + 2 * j) * DD + n];
        float b = W[(kc + 2 * j + 1) * DD + n];
        r[j] = packbf(a, b);
    }
    *(uint4*)(Wt + n * DD + kc) = make_uint4(r[0], r[1], r[2], r[3]);
}

// ---------------------------------------------------------------------------
// Gather SpMM (CSR, bf16): one row per 16-lane group, 8 bf16 (16B) per lane.
// fp32 accumulate, bf16 output.
// ---------------------------------------------------------------------------
__device__ __forceinline__ void accum8(float* acc, uint4 u, float v) {
    acc[0] += v * bf_lo(u.x); acc[1] += v * bf_hi(u.x);
    acc[2] += v * bf_lo(u.y); acc[3] += v * bf_hi(u.y);
    acc[4] += v * bf_lo(u.z); acc[5] += v * bf_hi(u.z);
    acc[6] += v * bf_lo(u.w); acc[7] += v * bf_hi(u.w);
}

__global__ __launch_bounds__(256) void spmm_bf16(
    const uint4* __restrict__ x, const int* __restrict__ row_ptr,
    const int* __restrict__ colp, const float* __restrict__ valp,
    uint4* __restrict__ out, int N)
{
    int t = blockIdx.x * 256 + threadIdx.x;
    int g = t >> 4;
    int lane = t & 15;
    if (g >= N) return;

    int s = row_ptr[g];
    int e = row_ptr[g + 1];
    float acc[8] = {0.f, 0.f, 0.f, 0.f, 0.f, 0.f, 0.f, 0.f};

    int k = s;
    for (; k + 4 <= e; k += 4) {
        int c0 = colp[k + 0], c1 = colp[k + 1], c2 = colp[k + 2], c3 = colp[k + 3];
        float v0 = valp[k + 0], v1 = valp[k + 1], v2 = valp[k + 2], v3 = valp[k + 3];
        uint4 A = x[(size_t)c0 * 16 + lane];
        uint4 B = x[(size_t)c1 * 16 + lane];
        uint4 C = x[(size_t)c2 * 16 + lane];
        uint4 D = x[(size_t)c3 * 16 + lane];
        accum8(acc, A, v0); accum8(acc, B, v1);
        accum8(acc, C, v2); accum8(acc, D, v3);
    }
    for (; k < e; k++) {
        int c0 = colp[k];
        float v0 = valp[k];
        uint4 A = x[(size_t)c0 * 16 + lane];
        accum8(acc, A, v0);
    }

    uint4 o;
    o.x = packbf(acc[0], acc[1]); o.y = packbf(acc[2], acc[3]);
    o.z = packbf(acc[4], acc[5]); o.w = packbf(acc[6], acc[7]);
    out[(size_t)g * 16 + lane] = o;
}

// ---------------------------------------------------------------------------
// Fused dense via bf16 MFMA 16x16x32. Block = 4 waves; wave = 16 rows x 128 cols.
// A-frags direct from global (read-once); B-frags from transposed Wt (L1/L2).
// Per-row batchnorm via C-layout (col=lane&15, row=quad*4+reg): register sum
// over 8 col-tiles + shfl_xor{1,2,4,8} within the 16-lane column group.
// ---------------------------------------------------------------------------
__global__ __launch_bounds__(256) void fused_dense_mfma(
    const unsigned short* __restrict__ h0,
    const unsigned short* __restrict__ h1,
    const unsigned short* __restrict__ h2,
    const unsigned short* __restrict__ Wt,   // [3][128][128] bf16, [o][n][k]
    const float* __restrict__ b0, const float* __restrict__ b1,
    const float* __restrict__ b2,
    const float* __restrict__ off0, const float* __restrict__ off1,
    const float* __restrict__ off2,
    const float* __restrict__ sc0, const float* __restrict__ sc1,
    const float* __restrict__ sc2,
    float* __restrict__ out, int N)
{
    const int tid  = threadIdx.x;
    const int wave = tid >> 6;
    const int lane = tid & 63;
    const int i    = lane & 15;   // tile col / A-row
    const int q    = lane >> 4;   // quad
    const int slab = blockIdx.x * 64 + wave * 16;

    int arow = slab + i;
    if (arow >= N) arow = N - 1;

    const unsigned short* hops[3] = {h0, h1, h2};
    const float* bs[3]  = {b0, b1, b2};
    const float* ofs[3] = {off0, off1, off2};
    const float* scs[3] = {sc0, sc1, sc2};

    float facc[8][4];
    #pragma unroll
    for (int ct = 0; ct < 8; ct++)
        #pragma unroll
        for (int r = 0; r < 4; r++) facc[ct][r] = 0.f;

    for (int o = 0; o < 3; o++) {
        const unsigned short* H  = hops[o];
        const unsigned short* Wo = Wt + o * (DD * DD);

        f32x4 acc[8];
        #pragma unroll
        for (int ct = 0; ct < 8; ct++) acc[ct] = (f32x4){0.f, 0.f, 0.f, 0.f};

        const unsigned short* arow_p = H + (size_t)arow * DD + q * 8;
        #pragma unroll
        for (int kb = 0; kb < 4; kb++) {
            bf16x8 a = *(const bf16x8*)(arow_p + kb * 32);
            #pragma unroll
            for (int ct = 0; ct < 8; ct++) {
                bf16x8 b = *(const bf16x8*)(Wo + (ct * 16 + i) * DD + kb * 32 + q * 8);
                acc[ct] = __builtin_amdgcn_mfma_f32_16x16x32_bf16(a, b, acc[ct], 0, 0, 0);
            }
        }

        float bc[8], sv[8], ov[8];
        #pragma unroll
        for (int ct = 0; ct < 8; ct++) {
            int c = ct * 16 + i;
            bc[ct] = bs[o][c]; sv[ct] = scs[o][c]; ov[ct] = ofs[o][c];
        }
        float s[4] = {0.f, 0.f, 0.f, 0.f};
        float qq[4] = {0.f, 0.f, 0.f, 0.f};
        #pragma unroll
        for (int ct = 0; ct < 8; ct++) {
            #pragma unroll
            for (int r = 0; r < 4; r++) {
                float v = fmaxf(acc[ct][r] + bc[ct], 0.f);
                acc[ct][r] = v;
                s[r] += v;
                qq[r] += v * v;
            }
        }
        #pragma unroll
        for (int r = 0; r < 4; r++) {
            #pragma unroll
            for (int m = 1; m <= 8; m <<= 1) {
                s[r]  += __shfl_xor(s[r],  m, 64);
                qq[r] += __shfl_xor(qq[r], m, 64);
            }
        }
        float rs[4], mn[4];
        #pragma unroll
        for (int r = 0; r < 4; r++) {
            mn[r] = s[r] * 0.0078125f;
            float var = qq[r] * 0.0078125f - mn[r] * mn[r];
            rs[r] = rsqrtf(var + 1e-9f);
        }
        #pragma unroll
        for (int ct = 0; ct < 8; ct++)
            #pragma unroll
            for (int r = 0; r < 4; r++)
                facc[ct][r] += sv[ct] * (acc[ct][r] - mn[r]) * rs[r] + ov[ct];
    }

    #pragma unroll
    for (int r = 0; r < 4; r++) {
        int orow = slab + q * 4 + r;
        if (orow < N) {
            float* op = out + (size_t)orow * DD + i;
            #pragma unroll
            for (int ct = 0; ct < 8; ct++) op[ct * 16] = facc[ct][r];
        }
    }
}

extern "C" void kernel_launch(void* const* d_in, const int* in_sizes, int n_in,
                              void* d_out, int out_size, void* d_ws, size_t ws_size,
                              hipStream_t stream)
{
    const float* vecs = (const float*)d_in[0];
    const float* adj  = (const float*)d_in[1];
    const int*   row  = (const int*)d_in[2];
    const int*   col  = (const int*)d_in[3];
    const float* W0   = (const float*)d_in[4];
    const float* b0   = (const float*)d_in[5];
    const float* off0 = (const float*)d_in[6];
    const float* sc0  = (const float*)d_in[7];
    const float* W1   = (const float*)d_in[8];
    const float* b1   = (const float*)d_in[9];
    const float* off1 = (const float*)d_in[10];
    const float* sc1  = (const float*)d_in[11];
    const float* W2   = (const float*)d_in[12];
    const float* b2   = (const float*)d_in[13];
    const float* off2 = (const float*)d_in[14];
    const float* sc2  = (const float*)d_in[15];

    const int E = in_sizes[1];
    const int N = NN;

    // Workspace layout (all 16B-aligned)
    unsigned short* hop1_bf = (unsigned short*)d_ws;          // N*128 bf16
    unsigned short* hop2_bf = hop1_bf + (size_t)N * DD;       // N*128 bf16
    unsigned short* vecs_bf = hop2_bf + (size_t)N * DD;       // N*128 bf16
    unsigned short* Wt_bf   = vecs_bf + (size_t)N * DD;       // 3*128*128 bf16
    int*   row_ptr  = (int*)(Wt_bf + 3 * DD * DD);            // RP_PAD
    int*   cursor   = row_ptr + RP_PAD;                       // RP_PAD
    int*   colp     = cursor + RP_PAD;                        // E
    float* valp     = (float*)(colp + E);                     // E
    int*   blocksum = (int*)(valp + E);                       // <=128

    hipMemsetAsync(cursor, 0, (size_t)N * sizeof(int), stream);

    // Converters (independent of CSR build)
    const int n8 = N * DD / 8;
    cvt_bf16<<<(n8 + 255) / 256, 256, 0, stream>>>(
        (const float4*)vecs, (uint4*)vecs_bf, n8);
    cvt_w<<<8, 256, 0, stream>>>(W0, Wt_bf);
    cvt_w<<<8, 256, 0, stream>>>(W1, Wt_bf + DD * DD);
    cvt_w<<<8, 256, 0, stream>>>(W2, Wt_bf + 2 * DD * DD);

    // CSR build
    const int snb = (N + 1023) / 1024;
    int eb = (E + 255) / 256;
    hist_rows<<<eb, 256, 0, stream>>>(row, cursor, E);
    scan_partial<<<snb, 256, 0, stream>>>(cursor, blocksum, N);
    scan_mid<<<1, 128, 0, stream>>>(blocksum, row_ptr, snb, N);
    scan_local<<<snb, 256, 0, stream>>>(cursor, blocksum, row_ptr, cursor, N);
    scatter_edges<<<eb, 256, 0, stream>>>(row, col, adj, cursor, colp, valp, E);

    // SpMM hops (bf16 in/out, fp32 accumulate)
    int sb = (N * 16 + 255) / 256;
    spmm_bf16<<<sb, 256, 0, stream>>>(
        (const uint4*)vecs_bf, row_ptr, colp, valp, (uint4*)hop1_bf, N);
    spmm_bf16<<<sb, 256, 0, stream>>>(
        (const uint4*)hop1_bf, row_ptr, colp, valp, (uint4*)hop2_bf, N);

    // Fused dense (MFMA)
    int db = (N + 63) / 64;
    fused_dense_mfma<<<db, 256, 0, stream>>>(
        vecs_bf, hop1_bf, hop2_bf, Wt_bf,
        b0, b1, b2, off0, off1, off2, sc0, sc1, sc2,
        (float*)d_out, N);
}